// Round 18
// baseline (189.311 us; speedup 1.0000x reference)
//
#include <hip/hip_runtime.h>
#include <math.h>

#define FFN_DIM 4096
#define NCHUNK  128        // 4096 / 32
#define PREPS   192        // probe iterations (6x real per-wave chunk count)

typedef _Float16 f16x8 __attribute__((ext_vector_type(8)));
typedef __fp16   h16x2 __attribute__((ext_vector_type(2)));
typedef float    f32x16 __attribute__((ext_vector_type(16)));
typedef float    f32x4  __attribute__((ext_vector_type(4)));
typedef int      i32x4v __attribute__((ext_vector_type(4)));

// ---------------------------------------------------------------------------
// Pre-kernel: build fp16 MFMA fragment tables in workspace. (verified)
// ---------------------------------------------------------------------------
__global__ void build_frags_kernel(const float* __restrict__ w1,
                                   const float* __restrict__ b1,
                                   const float* __restrict__ w2,
                                   _Float16* __restrict__ w1f,
                                   _Float16* __restrict__ w2f) {
    int i = blockIdx.x * 256 + threadIdx.x;
    if (i < NCHUNK * 64 * 8) {              // 65536
        int j    = i & 7;
        int lane = (i >> 3) & 63;
        int cc   = i >> 9;
        _Float16 v;
        if (lane < 32) v = (_Float16)w1[(cc * 32 + lane) * 8 + j];
        else           v = (j == 0) ? (_Float16)b1[cc * 32 + (lane & 31)]
                                    : (_Float16)0.0f;
        w1f[i] = v;
    }
    if (i < NCHUNK * 2 * 16 * 8) {          // 32768
        int j  = i & 7;
        int ci = (i >> 3) & 15;
        int c  = (i >> 7) & 1;
        int cc = i >> 8;
        int g = ci >> 3, e = ci & 7;
        int k = 8 * g + j;
        int fl = (k & 3) + 8 * ((k >> 2) & 1) + 4 * (k >> 3);
        int f = 32 * cc + 16 * c + fl;
        w2f[i] = (_Float16)w2[e * FFN_DIM + f];
    }
}

// ---------------------------------------------------------------------------
// PRODUCTION kernel: R16 exactly (best: 33.1us). 4 waves x 4 tiles, f-split.
// ---------------------------------------------------------------------------
__global__ __launch_bounds__(256, 2) void ffq_mfma_kernel(
    const float* __restrict__ x,
    const float* __restrict__ theta,
    const _Float16* __restrict__ w1f,   // [128][64][8]
    const _Float16* __restrict__ w2f,   // [128][2][16][8]
    const float* __restrict__ b2,
    float* __restrict__ out,
    int n_tok)
{
    __shared__ float part[4][4][64][4];    // 16KB

    const int tid  = threadIdx.x;
    const int lane = tid & 63;
    const int wave = tid >> 6;
    const int l31  = lane & 31;
    const int g    = lane >> 5;

    const int tb = blockIdx.x * 128;
    const float cth = cosf(theta[0]);

    f16x8 bq0 = {}, bq1 = {}, bq2 = {}, bq3 = {};
    if (g == 0) {
#define LOAD_BQ(BQ, TOFF)                                                  \
        {                                                                  \
            int t_ = tb + (TOFF) + l31;                                    \
            int r_ = t_ < n_tok ? t_ : (n_tok - 1);                        \
            const f32x4* xp_ = (const f32x4*)(x + (size_t)r_ * 8);         \
            f32x4 u_ = xp_[0], v_ = xp_[1];                                \
            BQ[0] = (_Float16)(cth * cosf(u_.x));                          \
            BQ[1] = (_Float16)(cth * cosf(u_.y));                          \
            BQ[2] = (_Float16)(cth * cosf(u_.z));                          \
            BQ[3] = (_Float16)(cth * cosf(u_.w));                          \
            BQ[4] = (_Float16)(cth * cosf(v_.x));                          \
            BQ[5] = (_Float16)(cth * cosf(v_.y));                          \
            BQ[6] = (_Float16)(cth * cosf(v_.z));                          \
            BQ[7] = (_Float16)(cth * cosf(v_.w));                          \
        }
        LOAD_BQ(bq0, 0)
        LOAD_BQ(bq1, 32)
        LOAD_BQ(bq2, 64)
        LOAD_BQ(bq3, 96)
#undef LOAD_BQ
    } else {
        bq0[0] = (_Float16)1.0f;
        bq1[0] = (_Float16)1.0f;
        bq2[0] = (_Float16)1.0f;
        bq3[0] = (_Float16)1.0f;
    }

    f32x16 acc0 = {}, acc1 = {}, acc2 = {}, acc3 = {};
    const f32x16 zero16 = {};

    const int ci = g * 8 + (l31 & 7);
    const _Float16* a1p = w1f + (size_t)lane * 8;
    const _Float16* a2p = w2f + (size_t)ci * 8;

    union U8 { f16x8 v; h16x2 p[4]; };
    const h16x2 hz = {(__fp16)0.0f, (__fp16)0.0f};

    const int c0 = wave * (NCHUNK / 4);
    const int c1 = c0 + (NCHUNK / 4);

    f16x8 A1  = *(const f16x8*)(a1p + (size_t)c0 * 512);
    f16x8 A2a = *(const f16x8*)(a2p + (size_t)c0 * 256);
    f16x8 A2b = *(const f16x8*)(a2p + (size_t)c0 * 256 + 128);

    for (int cc = c0; cc < c1; ++cc) {
        f16x8 nA1 = A1, nA2a = A2a, nA2b = A2b;
        if (cc + 1 < c1) {
            nA1  = *(const f16x8*)(a1p + (size_t)(cc + 1) * 512);
            nA2a = *(const f16x8*)(a2p + (size_t)(cc + 1) * 256);
            nA2b = *(const f16x8*)(a2p + (size_t)(cc + 1) * 256 + 128);
        }

        f32x16 dA = __builtin_amdgcn_mfma_f32_32x32x16_f16(A1, bq0, zero16, 0, 0, 0);
        f32x16 dB = __builtin_amdgcn_mfma_f32_32x32x16_f16(A1, bq1, zero16, 0, 0, 0);
        f32x16 dC = __builtin_amdgcn_mfma_f32_32x32x16_f16(A1, bq2, zero16, 0, 0, 0);
        f32x16 dD = __builtin_amdgcn_mfma_f32_32x32x16_f16(A1, bq3, zero16, 0, 0, 0);

        U8 uaA, ubA, uaB, ubB, uaC, ubC, uaD, ubD;
        #pragma unroll
        for (int v = 0; v < 4; ++v) {
            uaA.p[v] = __builtin_amdgcn_cvt_pkrtz(dA[2 * v],     dA[2 * v + 1]);
            ubA.p[v] = __builtin_amdgcn_cvt_pkrtz(dA[8 + 2 * v], dA[8 + 2 * v + 1]);
            uaB.p[v] = __builtin_amdgcn_cvt_pkrtz(dB[2 * v],     dB[2 * v + 1]);
            ubB.p[v] = __builtin_amdgcn_cvt_pkrtz(dB[8 + 2 * v], dB[8 + 2 * v + 1]);
            uaC.p[v] = __builtin_amdgcn_cvt_pkrtz(dC[2 * v],     dC[2 * v + 1]);
            ubC.p[v] = __builtin_amdgcn_cvt_pkrtz(dC[8 + 2 * v], dC[8 + 2 * v + 1]);
            uaD.p[v] = __builtin_amdgcn_cvt_pkrtz(dD[2 * v],     dD[2 * v + 1]);
            ubD.p[v] = __builtin_amdgcn_cvt_pkrtz(dD[8 + 2 * v], dD[8 + 2 * v + 1]);
        }
        #pragma unroll
        for (int v = 0; v < 4; ++v) {
            uaA.p[v] = __builtin_elementwise_max(uaA.p[v], hz);
            ubA.p[v] = __builtin_elementwise_max(ubA.p[v], hz);
            uaB.p[v] = __builtin_elementwise_max(uaB.p[v], hz);
            ubB.p[v] = __builtin_elementwise_max(ubB.p[v], hz);
            uaC.p[v] = __builtin_elementwise_max(uaC.p[v], hz);
            ubC.p[v] = __builtin_elementwise_max(ubC.p[v], hz);
            uaD.p[v] = __builtin_elementwise_max(uaD.p[v], hz);
            ubD.p[v] = __builtin_elementwise_max(ubD.p[v], hz);
        }

        acc0 = __builtin_amdgcn_mfma_f32_32x32x16_f16(A2a, uaA.v, acc0, 0, 0, 0);
        acc1 = __builtin_amdgcn_mfma_f32_32x32x16_f16(A2a, uaB.v, acc1, 0, 0, 0);
        acc2 = __builtin_amdgcn_mfma_f32_32x32x16_f16(A2a, uaC.v, acc2, 0, 0, 0);
        acc3 = __builtin_amdgcn_mfma_f32_32x32x16_f16(A2a, uaD.v, acc3, 0, 0, 0);
        acc0 = __builtin_amdgcn_mfma_f32_32x32x16_f16(A2b, ubA.v, acc0, 0, 0, 0);
        acc1 = __builtin_amdgcn_mfma_f32_32x32x16_f16(A2b, ubB.v, acc1, 0, 0, 0);
        acc2 = __builtin_amdgcn_mfma_f32_32x32x16_f16(A2b, ubC.v, acc2, 0, 0, 0);
        acc3 = __builtin_amdgcn_mfma_f32_32x32x16_f16(A2b, ubD.v, acc3, 0, 0, 0);

        A1 = nA1; A2a = nA2a; A2b = nA2b;
    }

    #pragma unroll
    for (int r = 0; r < 4; ++r) {
        part[wave][0][lane][r] = acc0[r];
        part[wave][1][lane][r] = acc1[r];
        part[wave][2][lane][r] = acc2[r];
        part[wave][3][lane][r] = acc3[r];
    }
    __syncthreads();

    for (int i = tid; i < 128 * 8; i += 256) {
        int t = i >> 3, e = i & 7;
        int gt = tb + t;
        if (gt < n_tok) {
            int tt = t >> 5;
            int tl = t & 31;
            int sl = (e >> 2) * 32 + tl;
            int r  = e & 3;
            float s = part[0][tt][sl][r] + part[1][tt][sl][r]
                    + part[2][tt][sl][r] + part[3][tt][sl][r] + b2[e];
            out[(size_t)gt * 8 + e] = s;
        }
    }
}

// ---------------------------------------------------------------------------
// PROBE A: pure MFMA issue throughput at the production wave shape.
// 12 MFMAs/iter into 8 accumulators (dep distance >= 6 MFMA), constant
// operands, no pack, no loads in loop. Writes to ws only.
// Model: 2 waves/SIMD x PREPS x 12 x ~34 cyc => ~65us. >>65 ==> H1.
// ---------------------------------------------------------------------------
__global__ __launch_bounds__(256, 2) void probe_mfma_tp(
    const _Float16* __restrict__ w1f,
    const _Float16* __restrict__ w2f,
    float* __restrict__ outp)
{
    const int tid  = threadIdx.x;
    const int lane = tid & 63;

    f16x8 A1  = *(const f16x8*)(w1f + (size_t)lane * 8);
    f16x8 A2a = *(const f16x8*)(w2f + (size_t)(lane & 15) * 8);
    f16x8 A2b = *(const f16x8*)(w2f + (size_t)(lane & 15) * 8 + 128);
    f16x8 b0 = {}, b1 = {}, b2v = {}, b3 = {};
    b0[0] = (_Float16)1.0f;  b1[0] = (_Float16)0.5f;
    b2v[0] = (_Float16)0.25f; b3[0] = (_Float16)0.125f;
    f16x8 u0 = *(const f16x8*)(w2f + 256);
    f16x8 u1 = *(const f16x8*)(w2f + 512);
    f16x8 u2 = *(const f16x8*)(w2f + 768);
    f16x8 u3 = *(const f16x8*)(w2f + 1024);

    f32x16 d0 = {}, d1 = {}, d2 = {}, d3 = {};
    f32x16 a0 = {}, a1 = {}, a2 = {}, a3 = {};

    for (int cc = 0; cc < PREPS; ++cc) {
        d0 = __builtin_amdgcn_mfma_f32_32x32x16_f16(A1, b0, d0, 0, 0, 0);
        d1 = __builtin_amdgcn_mfma_f32_32x32x16_f16(A1, b1, d1, 0, 0, 0);
        d2 = __builtin_amdgcn_mfma_f32_32x32x16_f16(A1, b2v, d2, 0, 0, 0);
        d3 = __builtin_amdgcn_mfma_f32_32x32x16_f16(A1, b3, d3, 0, 0, 0);
        a0 = __builtin_amdgcn_mfma_f32_32x32x16_f16(A2a, u0, a0, 0, 0, 0);
        a1 = __builtin_amdgcn_mfma_f32_32x32x16_f16(A2a, u1, a1, 0, 0, 0);
        a2 = __builtin_amdgcn_mfma_f32_32x32x16_f16(A2a, u2, a2, 0, 0, 0);
        a3 = __builtin_amdgcn_mfma_f32_32x32x16_f16(A2a, u3, a3, 0, 0, 0);
        a0 = __builtin_amdgcn_mfma_f32_32x32x16_f16(A2b, u0, a0, 0, 0, 0);
        a1 = __builtin_amdgcn_mfma_f32_32x32x16_f16(A2b, u1, a1, 0, 0, 0);
        a2 = __builtin_amdgcn_mfma_f32_32x32x16_f16(A2b, u2, a2, 0, 0, 0);
        a3 = __builtin_amdgcn_mfma_f32_32x32x16_f16(A2b, u3, a3, 0, 0, 0);
    }

    f32x16 s = d0 + d1 + d2 + d3 + a0 + a1 + a2 + a3;
    f32x4 r = {s[0] + s[4] + s[8] + s[12], s[1] + s[5] + s[9] + s[13],
               s[2] + s[6] + s[10] + s[14], s[3] + s[7] + s[11] + s[15]};
    ((f32x4*)outp)[blockIdx.x * 256 + tid] = r;
}

// ---------------------------------------------------------------------------
// PROBE B: production dataflow (G1 -> pack -> G2) with constant operands,
// no loads in loop. LICM defeated by xor-perturbing bq each iteration.
// probe_dep - probe_tp = dependency/pack cost. Writes to ws only.
// ---------------------------------------------------------------------------
__global__ __launch_bounds__(256, 2) void probe_mfma_dep(
    const _Float16* __restrict__ w1f,
    const _Float16* __restrict__ w2f,
    float* __restrict__ outp)
{
    const int tid  = threadIdx.x;
    const int lane = tid & 63;

    f16x8 A1  = *(const f16x8*)(w1f + (size_t)lane * 8);
    f16x8 A2a = *(const f16x8*)(w2f + (size_t)(lane & 15) * 8);
    f16x8 A2b = *(const f16x8*)(w2f + (size_t)(lane & 15) * 8 + 128);

    union HB { f16x8 h; i32x4v i; };
    HB b0, b1, b2v, b3;
    b0.h = {}; b1.h = {}; b2v.h = {}; b3.h = {};
    b0.h[0] = (_Float16)1.0f;  b1.h[0] = (_Float16)0.5f;
    b2v.h[0] = (_Float16)0.25f; b3.h[0] = (_Float16)0.125f;

    f32x16 a0 = {}, a1 = {}, a2 = {}, a3 = {};
    const f32x16 zero16 = {};
    union U8 { f16x8 v; h16x2 p[4]; };
    const h16x2 hz = {(__fp16)0.0f, (__fp16)0.0f};

    for (int cc = 0; cc < PREPS; ++cc) {
        // defeat loop-invariant hoisting (4 cheap VALU ops)
        b0.i.x ^= cc; b1.i.x ^= cc; b2v.i.x ^= cc; b3.i.x ^= cc;

        f32x16 dA = __builtin_amdgcn_mfma_f32_32x32x16_f16(A1, b0.h, zero16, 0, 0, 0);
        f32x16 dB = __builtin_amdgcn_mfma_f32_32x32x16_f16(A1, b1.h, zero16, 0, 0, 0);
        f32x16 dC = __builtin_amdgcn_mfma_f32_32x32x16_f16(A1, b2v.h, zero16, 0, 0, 0);
        f32x16 dD = __builtin_amdgcn_mfma_f32_32x32x16_f16(A1, b3.h, zero16, 0, 0, 0);

        U8 uaA, ubA, uaB, ubB, uaC, ubC, uaD, ubD;
        #pragma unroll
        for (int v = 0; v < 4; ++v) {
            uaA.p[v] = __builtin_amdgcn_cvt_pkrtz(dA[2 * v],     dA[2 * v + 1]);
            ubA.p[v] = __builtin_amdgcn_cvt_pkrtz(dA[8 + 2 * v], dA[8 + 2 * v + 1]);
            uaB.p[v] = __builtin_amdgcn_cvt_pkrtz(dB[2 * v],     dB[2 * v + 1]);
            ubB.p[v] = __builtin_amdgcn_cvt_pkrtz(dB[8 + 2 * v], dB[8 + 2 * v + 1]);
            uaC.p[v] = __builtin_amdgcn_cvt_pkrtz(dC[2 * v],     dC[2 * v + 1]);
            ubC.p[v] = __builtin_amdgcn_cvt_pkrtz(dC[8 + 2 * v], dC[8 + 2 * v + 1]);
            uaD.p[v] = __builtin_amdgcn_cvt_pkrtz(dD[2 * v],     dD[2 * v + 1]);
            ubD.p[v] = __builtin_amdgcn_cvt_pkrtz(dD[8 + 2 * v], dD[8 + 2 * v + 1]);
        }
        #pragma unroll
        for (int v = 0; v < 4; ++v) {
            uaA.p[v] = __builtin_elementwise_max(uaA.p[v], hz);
            ubA.p[v] = __builtin_elementwise_max(ubA.p[v], hz);
            uaB.p[v] = __builtin_elementwise_max(uaB.p[v], hz);
            ubB.p[v] = __builtin_elementwise_max(ubB.p[v], hz);
            uaC.p[v] = __builtin_elementwise_max(uaC.p[v], hz);
            ubC.p[v] = __builtin_elementwise_max(ubC.p[v], hz);
            uaD.p[v] = __builtin_elementwise_max(uaD.p[v], hz);
            ubD.p[v] = __builtin_elementwise_max(ubD.p[v], hz);
        }

        a0 = __builtin_amdgcn_mfma_f32_32x32x16_f16(A2a, uaA.v, a0, 0, 0, 0);
        a1 = __builtin_amdgcn_mfma_f32_32x32x16_f16(A2a, uaB.v, a1, 0, 0, 0);
        a2 = __builtin_amdgcn_mfma_f32_32x32x16_f16(A2a, uaC.v, a2, 0, 0, 0);
        a3 = __builtin_amdgcn_mfma_f32_32x32x16_f16(A2a, uaD.v, a3, 0, 0, 0);
        a0 = __builtin_amdgcn_mfma_f32_32x32x16_f16(A2b, ubA.v, a0, 0, 0, 0);
        a1 = __builtin_amdgcn_mfma_f32_32x32x16_f16(A2b, ubB.v, a1, 0, 0, 0);
        a2 = __builtin_amdgcn_mfma_f32_32x32x16_f16(A2b, ubC.v, a2, 0, 0, 0);
        a3 = __builtin_amdgcn_mfma_f32_32x32x16_f16(A2b, ubD.v, a3, 0, 0, 0);
    }

    f32x16 s = a0 + a1 + a2 + a3;
    f32x4 r = {s[0] + s[4] + s[8] + s[12], s[1] + s[5] + s[9] + s[13],
               s[2] + s[6] + s[10] + s[14], s[3] + s[7] + s[11] + s[15]};
    ((f32x4*)outp)[blockIdx.x * 256 + tid] = r;
}

// ---------------------------------------------------------------------------
// Fallback (ws too small): round-1 fp32 VALU kernel.
// ---------------------------------------------------------------------------
__global__ __launch_bounds__(256, 4) void ffq_valu_kernel(
    const float* __restrict__ x, const float* __restrict__ theta,
    const float* __restrict__ w1, const float* __restrict__ b1,
    const float* __restrict__ w2, const float* __restrict__ b2,
    float* __restrict__ out, int n_tok)
{
    __shared__ float part[4][64][9];
    const int tid = threadIdx.x;
    const int lane = tid & 63;
    const int wave = __builtin_amdgcn_readfirstlane(tid >> 6);
    const int tok = blockIdx.x * 64 + lane;
    const int rtok = tok < n_tok ? tok : n_tok - 1;
    const float cth = cosf(theta[0]);
    const f32x4* xv = (const f32x4*)(x + (size_t)rtok * 8);
    f32x4 x0 = xv[0], x1 = xv[1];
    float q[8];
    q[0]=cth*cosf(x0.x); q[1]=cth*cosf(x0.y); q[2]=cth*cosf(x0.z); q[3]=cth*cosf(x0.w);
    q[4]=cth*cosf(x1.x); q[5]=cth*cosf(x1.y); q[6]=cth*cosf(x1.z); q[7]=cth*cosf(x1.w);
    float acc[8];
    #pragma unroll
    for (int e = 0; e < 8; ++e) acc[e] = 0.0f;
    const int f0 = wave * (FFN_DIM / 4), f1 = f0 + (FFN_DIM / 4);
    #pragma unroll 2
    for (int f = f0; f < f1; ++f) {
        const f32x4* w1r = (const f32x4*)(w1 + (size_t)f * 8);
        f32x4 u0 = w1r[0], u1 = w1r[1];
        float h = b1[f];
        h = fmaf(u0.x,q[0],h); h = fmaf(u0.y,q[1],h); h = fmaf(u0.z,q[2],h); h = fmaf(u0.w,q[3],h);
        h = fmaf(u1.x,q[4],h); h = fmaf(u1.y,q[5],h); h = fmaf(u1.z,q[6],h); h = fmaf(u1.w,q[7],h);
        h = fmaxf(h, 0.0f);
        #pragma unroll
        for (int e = 0; e < 8; ++e) acc[e] = fmaf(h, w2[e * FFN_DIM + f], acc[e]);
    }
    #pragma unroll
    for (int e = 0; e < 8; ++e) part[wave][lane][e] = acc[e];
    __syncthreads();
    for (int i = tid; i < 64 * 8; i += 256) {
        int t = i >> 3, e = i & 7;
        int gt = blockIdx.x * 64 + t;
        if (gt < n_tok)
            out[(size_t)gt * 8 + e] = part[0][t][e] + part[1][t][e]
                                    + part[2][t][e] + part[3][t][e] + b2[e];
    }
}

extern "C" void kernel_launch(void* const* d_in, const int* in_sizes, int n_in,
                              void* d_out, int out_size, void* d_ws, size_t ws_size,
                              hipStream_t stream) {
    const float* x     = (const float*)d_in[0];
    const float* theta = (const float*)d_in[1];
    const float* w1    = (const float*)d_in[2];
    const float* b1    = (const float*)d_in[3];
    const float* w2    = (const float*)d_in[4];
    const float* b2    = (const float*)d_in[5];
    float* out = (float*)d_out;
    const int n_tok = out_size / 8;

    const size_t W1F_BYTES = (size_t)NCHUNK * 64 * 8 * sizeof(_Float16);   // 128KB
    const size_t W2F_BYTES = (size_t)NCHUNK * 2 * 16 * 8 * sizeof(_Float16); // 64KB

    if (ws_size >= W1F_BYTES + W2F_BYTES) {
        _Float16* w1f = (_Float16*)d_ws;
        _Float16* w2f = (_Float16*)((char*)d_ws + W1F_BYTES);
        build_frags_kernel<<<(NCHUNK * 64 * 8 + 255) / 256, 256, 0, stream>>>(
            w1, b1, w2, w1f, w2f);
        int blocks = (n_tok + 127) / 128;
        ffq_mfma_kernel<<<blocks, 256, 0, stream>>>(x, theta, w1f, w2f, b2, out,
                                                    n_tok);
        // ---- measurement probes (write only to ws; deterministic) ----
        if (ws_size >= (size_t)(8 << 20)) {
            float* pa = (float*)((char*)d_ws + (1 << 20));
            float* pb = (float*)((char*)d_ws + (4 << 20));
            probe_mfma_tp<<<512, 256, 0, stream>>>(w1f, w2f, pa);
            probe_mfma_dep<<<512, 256, 0, stream>>>(w1f, w2f, pb);
        }
    } else {
        int grid = (n_tok + 63) / 64;
        ffq_valu_kernel<<<grid, 256, 0, stream>>>(x, theta, w1, b1, w2, b2, out,
                                                  n_tok);
    }
}

// Round 19
// 85.913 us; speedup vs baseline: 2.2035x; 2.2035x over previous
//
#include <hip/hip_runtime.h>
#include <math.h>

#define FFN_DIM 4096
#define NCHUNK  128        // 4096 / 32

typedef _Float16 f16x8 __attribute__((ext_vector_type(8)));
typedef __fp16   h16x2 __attribute__((ext_vector_type(2)));
typedef float    f32x16 __attribute__((ext_vector_type(16)));
typedef float    f32x4  __attribute__((ext_vector_type(4)));

// ---------------------------------------------------------------------------
// Pre-kernel: build fp16 MFMA fragment tables in workspace. (verified)
// ---------------------------------------------------------------------------
__global__ void build_frags_kernel(const float* __restrict__ w1,
                                   const float* __restrict__ b1,
                                   const float* __restrict__ w2,
                                   _Float16* __restrict__ w1f,
                                   _Float16* __restrict__ w2f) {
    int i = blockIdx.x * 256 + threadIdx.x;
    if (i < NCHUNK * 64 * 8) {              // 65536
        int j    = i & 7;
        int lane = (i >> 3) & 63;
        int cc   = i >> 9;
        _Float16 v;
        if (lane < 32) v = (_Float16)w1[(cc * 32 + lane) * 8 + j];
        else           v = (j == 0) ? (_Float16)b1[cc * 32 + (lane & 31)]
                                    : (_Float16)0.0f;
        w1f[i] = v;
    }
    if (i < NCHUNK * 2 * 16 * 8) {          // 32768
        int j  = i & 7;
        int ci = (i >> 3) & 15;
        int c  = (i >> 7) & 1;
        int cc = i >> 8;
        int g = ci >> 3, e = ci & 7;
        int k = 8 * g + j;
        int fl = (k & 3) + 8 * ((k >> 2) & 1) + 4 * (k >> 3);
        int f = 32 * cc + 16 * c + fl;
        w2f[i] = (_Float16)w2[e * FFN_DIM + f];
    }
}

// ---------------------------------------------------------------------------
// Main kernel: R16's 4-tile structure, f-split ACROSS 2 BLOCK CLASSES for
// 4 waves/SIMD occupancy (probe-verified: the dataflow sustains 63% MfmaUtil;
// L2 load latency needs co-resident waves to hide under).
// Block b: cls = b&1 (chunks cls*64..cls*64+63), tokens (b>>1)*128..+127.
// Wave w owns 16 chunks x 4 tiles = 12 MFMA/chunk. Partials -> ws; reduce
// kernel sums the 2 classes + b2.
// ---------------------------------------------------------------------------
__global__ __launch_bounds__(256, 4) void ffq_mfma_kernel(
    const float* __restrict__ x,
    const float* __restrict__ theta,
    const _Float16* __restrict__ w1f,   // [128][64][8]
    const _Float16* __restrict__ w2f,   // [128][2][16][8]
    float* __restrict__ partial,        // [2][n_tok][8]
    int n_tok)
{
    __shared__ float part[4][4][64][4];    // 16KB

    const int tid  = threadIdx.x;
    const int lane = tid & 63;
    const int wave = tid >> 6;
    const int l31  = lane & 31;
    const int g    = lane >> 5;

    const int cls = blockIdx.x & 1;
    const int tb  = (blockIdx.x >> 1) * 128;
    const float cth = cosf(theta[0]);

    f16x8 bq0 = {}, bq1 = {}, bq2 = {}, bq3 = {};
    if (g == 0) {
#define LOAD_BQ(BQ, TOFF)                                                  \
        {                                                                  \
            int t_ = tb + (TOFF) + l31;                                    \
            int r_ = t_ < n_tok ? t_ : (n_tok - 1);                        \
            const f32x4* xp_ = (const f32x4*)(x + (size_t)r_ * 8);         \
            f32x4 u_ = xp_[0], v_ = xp_[1];                                \
            BQ[0] = (_Float16)(cth * cosf(u_.x));                          \
            BQ[1] = (_Float16)(cth * cosf(u_.y));                          \
            BQ[2] = (_Float16)(cth * cosf(u_.z));                          \
            BQ[3] = (_Float16)(cth * cosf(u_.w));                          \
            BQ[4] = (_Float16)(cth * cosf(v_.x));                          \
            BQ[5] = (_Float16)(cth * cosf(v_.y));                          \
            BQ[6] = (_Float16)(cth * cosf(v_.z));                          \
            BQ[7] = (_Float16)(cth * cosf(v_.w));                          \
        }
        LOAD_BQ(bq0, 0)
        LOAD_BQ(bq1, 32)
        LOAD_BQ(bq2, 64)
        LOAD_BQ(bq3, 96)
#undef LOAD_BQ
    } else {
        bq0[0] = (_Float16)1.0f;   // k=8 column: multiplies the b1 row of W1frag
        bq1[0] = (_Float16)1.0f;
        bq2[0] = (_Float16)1.0f;
        bq3[0] = (_Float16)1.0f;
    }

    f32x16 acc0 = {}, acc1 = {}, acc2 = {}, acc3 = {};
    const f32x16 zero16 = {};

    const int ci = g * 8 + (l31 & 7);
    const _Float16* a1p = w1f + (size_t)lane * 8;
    const _Float16* a2p = w2f + (size_t)ci * 8;

    union U8 { f16x8 v; h16x2 p[4]; };
    const h16x2 hz = {(__fp16)0.0f, (__fp16)0.0f};

    const int c0 = cls * 64 + wave * 16;
    const int c1 = c0 + 16;

    f16x8 A1  = *(const f16x8*)(a1p + (size_t)c0 * 512);
    f16x8 A2a = *(const f16x8*)(a2p + (size_t)c0 * 256);
    f16x8 A2b = *(const f16x8*)(a2p + (size_t)c0 * 256 + 128);

    for (int cc = c0; cc < c1; ++cc) {
        f16x8 nA1 = A1, nA2a = A2a, nA2b = A2b;
        if (cc + 1 < c1) {
            nA1  = *(const f16x8*)(a1p + (size_t)(cc + 1) * 512);
            nA2a = *(const f16x8*)(a2p + (size_t)(cc + 1) * 256);
            nA2b = *(const f16x8*)(a2p + (size_t)(cc + 1) * 256 + 128);
        }

        f32x16 dA = __builtin_amdgcn_mfma_f32_32x32x16_f16(A1, bq0, zero16, 0, 0, 0);
        f32x16 dB = __builtin_amdgcn_mfma_f32_32x32x16_f16(A1, bq1, zero16, 0, 0, 0);
        f32x16 dC = __builtin_amdgcn_mfma_f32_32x32x16_f16(A1, bq2, zero16, 0, 0, 0);
        f32x16 dD = __builtin_amdgcn_mfma_f32_32x32x16_f16(A1, bq3, zero16, 0, 0, 0);

        U8 uaA, ubA, uaB, ubB, uaC, ubC, uaD, ubD;
        #pragma unroll
        for (int v = 0; v < 4; ++v) {
            uaA.p[v] = __builtin_amdgcn_cvt_pkrtz(dA[2 * v],     dA[2 * v + 1]);
            ubA.p[v] = __builtin_amdgcn_cvt_pkrtz(dA[8 + 2 * v], dA[8 + 2 * v + 1]);
            uaB.p[v] = __builtin_amdgcn_cvt_pkrtz(dB[2 * v],     dB[2 * v + 1]);
            ubB.p[v] = __builtin_amdgcn_cvt_pkrtz(dB[8 + 2 * v], dB[8 + 2 * v + 1]);
            uaC.p[v] = __builtin_amdgcn_cvt_pkrtz(dC[2 * v],     dC[2 * v + 1]);
            ubC.p[v] = __builtin_amdgcn_cvt_pkrtz(dC[8 + 2 * v], dC[8 + 2 * v + 1]);
            uaD.p[v] = __builtin_amdgcn_cvt_pkrtz(dD[2 * v],     dD[2 * v + 1]);
            ubD.p[v] = __builtin_amdgcn_cvt_pkrtz(dD[8 + 2 * v], dD[8 + 2 * v + 1]);
        }
        #pragma unroll
        for (int v = 0; v < 4; ++v) {
            uaA.p[v] = __builtin_elementwise_max(uaA.p[v], hz);
            ubA.p[v] = __builtin_elementwise_max(ubA.p[v], hz);
            uaB.p[v] = __builtin_elementwise_max(uaB.p[v], hz);
            ubB.p[v] = __builtin_elementwise_max(ubB.p[v], hz);
            uaC.p[v] = __builtin_elementwise_max(uaC.p[v], hz);
            ubC.p[v] = __builtin_elementwise_max(ubC.p[v], hz);
            uaD.p[v] = __builtin_elementwise_max(uaD.p[v], hz);
            ubD.p[v] = __builtin_elementwise_max(ubD.p[v], hz);
        }

        acc0 = __builtin_amdgcn_mfma_f32_32x32x16_f16(A2a, uaA.v, acc0, 0, 0, 0);
        acc1 = __builtin_amdgcn_mfma_f32_32x32x16_f16(A2a, uaB.v, acc1, 0, 0, 0);
        acc2 = __builtin_amdgcn_mfma_f32_32x32x16_f16(A2a, uaC.v, acc2, 0, 0, 0);
        acc3 = __builtin_amdgcn_mfma_f32_32x32x16_f16(A2a, uaD.v, acc3, 0, 0, 0);
        acc0 = __builtin_amdgcn_mfma_f32_32x32x16_f16(A2b, ubA.v, acc0, 0, 0, 0);
        acc1 = __builtin_amdgcn_mfma_f32_32x32x16_f16(A2b, ubB.v, acc1, 0, 0, 0);
        acc2 = __builtin_amdgcn_mfma_f32_32x32x16_f16(A2b, ubC.v, acc2, 0, 0, 0);
        acc3 = __builtin_amdgcn_mfma_f32_32x32x16_f16(A2b, ubD.v, acc3, 0, 0, 0);

        A1 = nA1; A2a = nA2a; A2b = nA2b;
    }

    #pragma unroll
    for (int r = 0; r < 4; ++r) {
        part[wave][0][lane][r] = acc0[r];
        part[wave][1][lane][r] = acc1[r];
        part[wave][2][lane][r] = acc2[r];
        part[wave][3][lane][r] = acc3[r];
    }
    __syncthreads();

    // 1024 partial outputs per block (128 tok x 8 e); no b2 here
    for (int i = tid; i < 128 * 8; i += 256) {
        int t = i >> 3, e = i & 7;
        int gt = tb + t;
        if (gt < n_tok) {
            int tt = t >> 5;
            int tl = t & 31;
            int sl = (e >> 2) * 32 + tl;
            int r  = e & 3;
            float s = part[0][tt][sl][r] + part[1][tt][sl][r]
                    + part[2][tt][sl][r] + part[3][tt][sl][r];
            partial[((size_t)cls * n_tok + gt) * 8 + e] = s;
        }
    }
}

// ---------------------------------------------------------------------------
// Reduce: out = partial[0] + partial[1] + b2. One float4 per thread.
// ---------------------------------------------------------------------------
__global__ __launch_bounds__(256) void ffq_reduce_kernel(
    const float* __restrict__ partial, const float* __restrict__ b2,
    float* __restrict__ out, int n_tok)
{
    int j = blockIdx.x * 256 + threadIdx.x;    // float4 index
    int nq = n_tok * 2;
    if (j < nq) {
        const f32x4* p = (const f32x4*)partial;
        size_t stride = (size_t)n_tok * 2;
        f32x4 s = p[j] + p[j + stride];
        f32x4 bb = ((const f32x4*)b2)[j & 1];
        ((f32x4*)out)[j] = s + bb;
    }
}

// ---------------------------------------------------------------------------
// Fallback (ws too small): round-1 fp32 VALU kernel.
// ---------------------------------------------------------------------------
__global__ __launch_bounds__(256, 4) void ffq_valu_kernel(
    const float* __restrict__ x, const float* __restrict__ theta,
    const float* __restrict__ w1, const float* __restrict__ b1,
    const float* __restrict__ w2, const float* __restrict__ b2,
    float* __restrict__ out, int n_tok)
{
    __shared__ float part[4][64][9];
    const int tid = threadIdx.x;
    const int lane = tid & 63;
    const int wave = __builtin_amdgcn_readfirstlane(tid >> 6);
    const int tok = blockIdx.x * 64 + lane;
    const int rtok = tok < n_tok ? tok : n_tok - 1;
    const float cth = cosf(theta[0]);
    const f32x4* xv = (const f32x4*)(x + (size_t)rtok * 8);
    f32x4 x0 = xv[0], x1 = xv[1];
    float q[8];
    q[0]=cth*cosf(x0.x); q[1]=cth*cosf(x0.y); q[2]=cth*cosf(x0.z); q[3]=cth*cosf(x0.w);
    q[4]=cth*cosf(x1.x); q[5]=cth*cosf(x1.y); q[6]=cth*cosf(x1.z); q[7]=cth*cosf(x1.w);
    float acc[8];
    #pragma unroll
    for (int e = 0; e < 8; ++e) acc[e] = 0.0f;
    const int f0 = wave * (FFN_DIM / 4), f1 = f0 + (FFN_DIM / 4);
    #pragma unroll 2
    for (int f = f0; f < f1; ++f) {
        const f32x4* w1r = (const f32x4*)(w1 + (size_t)f * 8);
        f32x4 u0 = w1r[0], u1 = w1r[1];
        float h = b1[f];
        h = fmaf(u0.x,q[0],h); h = fmaf(u0.y,q[1],h); h = fmaf(u0.z,q[2],h); h = fmaf(u0.w,q[3],h);
        h = fmaf(u1.x,q[4],h); h = fmaf(u1.y,q[5],h); h = fmaf(u1.z,q[6],h); h = fmaf(u1.w,q[7],h);
        h = fmaxf(h, 0.0f);
        #pragma unroll
        for (int e = 0; e < 8; ++e) acc[e] = fmaf(h, w2[e * FFN_DIM + f], acc[e]);
    }
    #pragma unroll
    for (int e = 0; e < 8; ++e) part[wave][lane][e] = acc[e];
    __syncthreads();
    for (int i = tid; i < 64 * 8; i += 256) {
        int t = i >> 3, e = i & 7;
        int gt = blockIdx.x * 64 + t;
        if (gt < n_tok)
            out[(size_t)gt * 8 + e] = part[0][t][e] + part[1][t][e]
                                    + part[2][t][e] + part[3][t][e] + b2[e];
    }
}

extern "C" void kernel_launch(void* const* d_in, const int* in_sizes, int n_in,
                              void* d_out, int out_size, void* d_ws, size_t ws_size,
                              hipStream_t stream) {
    const float* x     = (const float*)d_in[0];
    const float* theta = (const float*)d_in[1];
    const float* w1    = (const float*)d_in[2];
    const float* b1    = (const float*)d_in[3];
    const float* w2    = (const float*)d_in[4];
    const float* b2    = (const float*)d_in[5];
    float* out = (float*)d_out;
    const int n_tok = out_size / 8;

    const size_t W1F_BYTES = (size_t)NCHUNK * 64 * 8 * sizeof(_Float16);     // 128KB
    const size_t W2F_BYTES = (size_t)NCHUNK * 2 * 16 * 8 * sizeof(_Float16); // 64KB
    const size_t PART_BYTES = (size_t)2 * n_tok * 8 * sizeof(float);         // 4MB

    if (ws_size >= W1F_BYTES + W2F_BYTES + PART_BYTES) {
        _Float16* w1f = (_Float16*)d_ws;
        _Float16* w2f = (_Float16*)((char*)d_ws + W1F_BYTES);
        float* partial = (float*)((char*)d_ws + W1F_BYTES + W2F_BYTES);
        build_frags_kernel<<<(NCHUNK * 64 * 8 + 255) / 256, 256, 0, stream>>>(
            w1, b1, w2, w1f, w2f);
        int blocks = 2 * ((n_tok + 127) / 128);   // 2 f-classes x token-groups
        ffq_mfma_kernel<<<blocks, 256, 0, stream>>>(x, theta, w1f, w2f,
                                                    partial, n_tok);
        int nq = n_tok * 2;
        ffq_reduce_kernel<<<(nq + 255) / 256, 256, 0, stream>>>(partial, b2,
                                                                out, n_tok);
    } else {
        int grid = (n_tok + 63) / 64;
        ffq_valu_kernel<<<grid, 256, 0, stream>>>(x, theta, w1, b1, w2, b2, out,
                                                  n_tok);
    }
}

// Round 20
// 33.027 us; speedup vs baseline: 5.7319x; 2.6013x over previous
//
#include <hip/hip_runtime.h>
#include <math.h>

#define FFN_DIM 4096
#define NCHUNK  128        // 4096 / 32

typedef _Float16 f16x8 __attribute__((ext_vector_type(8)));
typedef __fp16   h16x2 __attribute__((ext_vector_type(2)));
typedef float    f32x16 __attribute__((ext_vector_type(16)));
typedef float    f32x4  __attribute__((ext_vector_type(4)));

// ---------------------------------------------------------------------------
// Pre-kernel: build fp16 MFMA fragment tables in workspace. (verified)
//  w1f [128][64][8]: lanes 0-31 = W1 rows; lanes 32-63 = {b1,0..} (bias via
//  constant-1 k=8 column).  w2f [128][2][16][8]: W2 rows permuted to match
//  G1's C/D register order (absmax 3.9e-3 across rounds 7-19).
// ---------------------------------------------------------------------------
__global__ void build_frags_kernel(const float* __restrict__ w1,
                                   const float* __restrict__ b1,
                                   const float* __restrict__ w2,
                                   _Float16* __restrict__ w1f,
                                   _Float16* __restrict__ w2f) {
    int i = blockIdx.x * 256 + threadIdx.x;
    if (i < NCHUNK * 64 * 8) {              // 65536
        int j    = i & 7;
        int lane = (i >> 3) & 63;
        int cc   = i >> 9;
        _Float16 v;
        if (lane < 32) v = (_Float16)w1[(cc * 32 + lane) * 8 + j];
        else           v = (j == 0) ? (_Float16)b1[cc * 32 + (lane & 31)]
                                    : (_Float16)0.0f;
        w1f[i] = v;
    }
    if (i < NCHUNK * 2 * 16 * 8) {          // 32768
        int j  = i & 7;
        int ci = (i >> 3) & 15;
        int c  = (i >> 7) & 1;
        int cc = i >> 8;
        int g = ci >> 3, e = ci & 7;
        int k = 8 * g + j;
        int fl = (k & 3) + 8 * ((k >> 2) & 1) + 4 * (k >> 3);
        int f = 32 * cc + 16 * c + fl;
        w2f[i] = (_Float16)w2[e * FFN_DIM + f];
    }
}

// ---------------------------------------------------------------------------
// Main kernel: R16 structure (best verified: 33.1us) + ONE change:
// sched_barrier(0) after the prefetch loads. R18's probes showed the
// dataflow alone runs at 17us-equivalent (63% MfmaUtil); the 16us gap is
// 3 L2 latencies/iter exposed because the register-pressure-driven
// scheduler SINKS the prefetch loads to their use. The barrier pins them
// at iteration top so the body (~300-400cyc) covers the ~200cyc L2 latency.
// ---------------------------------------------------------------------------
__global__ __launch_bounds__(256, 2) void ffq_mfma_kernel(
    const float* __restrict__ x,
    const float* __restrict__ theta,
    const _Float16* __restrict__ w1f,   // [128][64][8]
    const _Float16* __restrict__ w2f,   // [128][2][16][8]
    const float* __restrict__ b2,
    float* __restrict__ out,
    int n_tok)
{
    __shared__ float part[4][4][64][4];    // 16KB

    const int tid  = threadIdx.x;
    const int lane = tid & 63;
    const int wave = tid >> 6;
    const int l31  = lane & 31;
    const int g    = lane >> 5;

    const int tb = blockIdx.x * 128;
    const float cth = cosf(theta[0]);

    f16x8 bq0 = {}, bq1 = {}, bq2 = {}, bq3 = {};
    if (g == 0) {
#define LOAD_BQ(BQ, TOFF)                                                  \
        {                                                                  \
            int t_ = tb + (TOFF) + l31;                                    \
            int r_ = t_ < n_tok ? t_ : (n_tok - 1);                        \
            const f32x4* xp_ = (const f32x4*)(x + (size_t)r_ * 8);         \
            f32x4 u_ = xp_[0], v_ = xp_[1];                                \
            BQ[0] = (_Float16)(cth * cosf(u_.x));                          \
            BQ[1] = (_Float16)(cth * cosf(u_.y));                          \
            BQ[2] = (_Float16)(cth * cosf(u_.z));                          \
            BQ[3] = (_Float16)(cth * cosf(u_.w));                          \
            BQ[4] = (_Float16)(cth * cosf(v_.x));                          \
            BQ[5] = (_Float16)(cth * cosf(v_.y));                          \
            BQ[6] = (_Float16)(cth * cosf(v_.z));                          \
            BQ[7] = (_Float16)(cth * cosf(v_.w));                          \
        }
        LOAD_BQ(bq0, 0)
        LOAD_BQ(bq1, 32)
        LOAD_BQ(bq2, 64)
        LOAD_BQ(bq3, 96)
#undef LOAD_BQ
    } else {
        bq0[0] = (_Float16)1.0f;   // k=8 column: multiplies the b1 row of W1frag
        bq1[0] = (_Float16)1.0f;
        bq2[0] = (_Float16)1.0f;
        bq3[0] = (_Float16)1.0f;
    }

    f32x16 acc0 = {}, acc1 = {}, acc2 = {}, acc3 = {};
    const f32x16 zero16 = {};

    const int ci = g * 8 + (l31 & 7);
    const _Float16* a1p = w1f + (size_t)lane * 8;
    const _Float16* a2p = w2f + (size_t)ci * 8;

    union U8 { f16x8 v; h16x2 p[4]; };
    const h16x2 hz = {(__fp16)0.0f, (__fp16)0.0f};

    const int c0 = wave * (NCHUNK / 4);
    const int c1 = c0 + (NCHUNK / 4);

    f16x8 A1  = *(const f16x8*)(a1p + (size_t)c0 * 512);
    f16x8 A2a = *(const f16x8*)(a2p + (size_t)c0 * 256);
    f16x8 A2b = *(const f16x8*)(a2p + (size_t)c0 * 256 + 128);

    for (int cc = c0; cc < c1; ++cc) {
        // ---- prefetch next chunk (branch-free; last iter re-loads itself) --
        int nx = (cc + 1 < c1) ? (cc + 1) : cc;
        f16x8 nA1  = *(const f16x8*)(a1p + (size_t)nx * 512);
        f16x8 nA2a = *(const f16x8*)(a2p + (size_t)nx * 256);
        f16x8 nA2b = *(const f16x8*)(a2p + (size_t)nx * 256 + 128);
        // Pin the loads at iteration top: forbid the pressure-driven
        // scheduler from sinking them to their (next-iteration) use.
        __builtin_amdgcn_sched_barrier(0);

        f32x16 dA = __builtin_amdgcn_mfma_f32_32x32x16_f16(A1, bq0, zero16, 0, 0, 0);
        f32x16 dB = __builtin_amdgcn_mfma_f32_32x32x16_f16(A1, bq1, zero16, 0, 0, 0);
        f32x16 dC = __builtin_amdgcn_mfma_f32_32x32x16_f16(A1, bq2, zero16, 0, 0, 0);
        f32x16 dD = __builtin_amdgcn_mfma_f32_32x32x16_f16(A1, bq3, zero16, 0, 0, 0);

        U8 uaA, ubA, uaB, ubB, uaC, ubC, uaD, ubD;
        #pragma unroll
        for (int v = 0; v < 4; ++v) {
            uaA.p[v] = __builtin_amdgcn_cvt_pkrtz(dA[2 * v],     dA[2 * v + 1]);
            ubA.p[v] = __builtin_amdgcn_cvt_pkrtz(dA[8 + 2 * v], dA[8 + 2 * v + 1]);
            uaB.p[v] = __builtin_amdgcn_cvt_pkrtz(dB[2 * v],     dB[2 * v + 1]);
            ubB.p[v] = __builtin_amdgcn_cvt_pkrtz(dB[8 + 2 * v], dB[8 + 2 * v + 1]);
            uaC.p[v] = __builtin_amdgcn_cvt_pkrtz(dC[2 * v],     dC[2 * v + 1]);
            ubC.p[v] = __builtin_amdgcn_cvt_pkrtz(dC[8 + 2 * v], dC[8 + 2 * v + 1]);
            uaD.p[v] = __builtin_amdgcn_cvt_pkrtz(dD[2 * v],     dD[2 * v + 1]);
            ubD.p[v] = __builtin_amdgcn_cvt_pkrtz(dD[8 + 2 * v], dD[8 + 2 * v + 1]);
        }
        #pragma unroll
        for (int v = 0; v < 4; ++v) {
            uaA.p[v] = __builtin_elementwise_max(uaA.p[v], hz);
            ubA.p[v] = __builtin_elementwise_max(ubA.p[v], hz);
            uaB.p[v] = __builtin_elementwise_max(uaB.p[v], hz);
            ubB.p[v] = __builtin_elementwise_max(ubB.p[v], hz);
            uaC.p[v] = __builtin_elementwise_max(uaC.p[v], hz);
            ubC.p[v] = __builtin_elementwise_max(ubC.p[v], hz);
            uaD.p[v] = __builtin_elementwise_max(uaD.p[v], hz);
            ubD.p[v] = __builtin_elementwise_max(ubD.p[v], hz);
        }

        acc0 = __builtin_amdgcn_mfma_f32_32x32x16_f16(A2a, uaA.v, acc0, 0, 0, 0);
        acc1 = __builtin_amdgcn_mfma_f32_32x32x16_f16(A2a, uaB.v, acc1, 0, 0, 0);
        acc2 = __builtin_amdgcn_mfma_f32_32x32x16_f16(A2a, uaC.v, acc2, 0, 0, 0);
        acc3 = __builtin_amdgcn_mfma_f32_32x32x16_f16(A2a, uaD.v, acc3, 0, 0, 0);
        acc0 = __builtin_amdgcn_mfma_f32_32x32x16_f16(A2b, ubA.v, acc0, 0, 0, 0);
        acc1 = __builtin_amdgcn_mfma_f32_32x32x16_f16(A2b, ubB.v, acc1, 0, 0, 0);
        acc2 = __builtin_amdgcn_mfma_f32_32x32x16_f16(A2b, ubC.v, acc2, 0, 0, 0);
        acc3 = __builtin_amdgcn_mfma_f32_32x32x16_f16(A2b, ubD.v, acc3, 0, 0, 0);

        A1 = nA1; A2a = nA2a; A2b = nA2b;
    }

    #pragma unroll
    for (int r = 0; r < 4; ++r) {
        part[wave][0][lane][r] = acc0[r];
        part[wave][1][lane][r] = acc1[r];
        part[wave][2][lane][r] = acc2[r];
        part[wave][3][lane][r] = acc3[r];
    }
    __syncthreads();

    // 1024 outputs per block (128 tok x 8 e), 4 per thread
    for (int i = tid; i < 128 * 8; i += 256) {
        int t = i >> 3, e = i & 7;
        int gt = tb + t;
        if (gt < n_tok) {
            int tt = t >> 5;
            int tl = t & 31;
            int sl = (e >> 2) * 32 + tl;
            int r  = e & 3;
            float s = part[0][tt][sl][r] + part[1][tt][sl][r]
                    + part[2][tt][sl][r] + part[3][tt][sl][r] + b2[e];
            out[(size_t)gt * 8 + e] = s;
        }
    }
}

// ---------------------------------------------------------------------------
// Fallback (ws too small): round-1 fp32 VALU kernel.
// ---------------------------------------------------------------------------
__global__ __launch_bounds__(256, 4) void ffq_valu_kernel(
    const float* __restrict__ x, const float* __restrict__ theta,
    const float* __restrict__ w1, const float* __restrict__ b1,
    const float* __restrict__ w2, const float* __restrict__ b2,
    float* __restrict__ out, int n_tok)
{
    __shared__ float part[4][64][9];
    const int tid = threadIdx.x;
    const int lane = tid & 63;
    const int wave = __builtin_amdgcn_readfirstlane(tid >> 6);
    const int tok = blockIdx.x * 64 + lane;
    const int rtok = tok < n_tok ? tok : n_tok - 1;
    const float cth = cosf(theta[0]);
    const f32x4* xv = (const f32x4*)(x + (size_t)rtok * 8);
    f32x4 x0 = xv[0], x1 = xv[1];
    float q[8];
    q[0]=cth*cosf(x0.x); q[1]=cth*cosf(x0.y); q[2]=cth*cosf(x0.z); q[3]=cth*cosf(x0.w);
    q[4]=cth*cosf(x1.x); q[5]=cth*cosf(x1.y); q[6]=cth*cosf(x1.z); q[7]=cth*cosf(x1.w);
    float acc[8];
    #pragma unroll
    for (int e = 0; e < 8; ++e) acc[e] = 0.0f;
    const int f0 = wave * (FFN_DIM / 4), f1 = f0 + (FFN_DIM / 4);
    #pragma unroll 2
    for (int f = f0; f < f1; ++f) {
        const f32x4* w1r = (const f32x4*)(w1 + (size_t)f * 8);
        f32x4 u0 = w1r[0], u1 = w1r[1];
        float h = b1[f];
        h = fmaf(u0.x,q[0],h); h = fmaf(u0.y,q[1],h); h = fmaf(u0.z,q[2],h); h = fmaf(u0.w,q[3],h);
        h = fmaf(u1.x,q[4],h); h = fmaf(u1.y,q[5],h); h = fmaf(u1.z,q[6],h); h = fmaf(u1.w,q[7],h);
        h = fmaxf(h, 0.0f);
        #pragma unroll
        for (int e = 0; e < 8; ++e) acc[e] = fmaf(h, w2[e * FFN_DIM + f], acc[e]);
    }
    #pragma unroll
    for (int e = 0; e < 8; ++e) part[wave][lane][e] = acc[e];
    __syncthreads();
    for (int i = tid; i < 64 * 8; i += 256) {
        int t = i >> 3, e = i & 7;
        int gt = blockIdx.x * 64 + t;
        if (gt < n_tok)
            out[(size_t)gt * 8 + e] = part[0][t][e] + part[1][t][e]
                                    + part[2][t][e] + part[3][t][e] + b2[e];
    }
}

extern "C" void kernel_launch(void* const* d_in, const int* in_sizes, int n_in,
                              void* d_out, int out_size, void* d_ws, size_t ws_size,
                              hipStream_t stream) {
    const float* x     = (const float*)d_in[0];
    const float* theta = (const float*)d_in[1];
    const float* w1    = (const float*)d_in[2];
    const float* b1    = (const float*)d_in[3];
    const float* w2    = (const float*)d_in[4];
    const float* b2    = (const float*)d_in[5];
    float* out = (float*)d_out;
    const int n_tok = out_size / 8;

    const size_t W1F_BYTES = (size_t)NCHUNK * 64 * 8 * sizeof(_Float16);   // 128KB
    const size_t W2F_BYTES = (size_t)NCHUNK * 2 * 16 * 8 * sizeof(_Float16); // 64KB

    if (ws_size >= W1F_BYTES + W2F_BYTES) {
        _Float16* w1f = (_Float16*)d_ws;
        _Float16* w2f = (_Float16*)((char*)d_ws + W1F_BYTES);
        build_frags_kernel<<<(NCHUNK * 64 * 8 + 255) / 256, 256, 0, stream>>>(
            w1, b1, w2, w1f, w2f);
        int blocks = (n_tok + 127) / 128;   // four 32-token tiles per block
        ffq_mfma_kernel<<<blocks, 256, 0, stream>>>(x, theta, w1f, w2f, b2, out,
                                                    n_tok);
    } else {
        int grid = (n_tok + 63) / 64;
        ffq_valu_kernel<<<grid, 256, 0, stream>>>(x, theta, w1, b1, w2, b2, out,
                                                  n_tok);
    }
}